// Round 1
// 667.832 us; speedup vs baseline: 1.1459x; 1.1459x over previous
//
#include <hip/hip_runtime.h>
#include <hip/hip_bf16.h>

#define Bq   16
#define Nseq 1024
#define Cdim 768
#define NH2  24
#define W2D  1536
#define KB   16
#define NMB  64

typedef short bfrag8 __attribute__((ext_vector_type(8)));   // 8 bf16 (4 VGPRs)
typedef short bfrag4 __attribute__((ext_vector_type(4)));   // 4 bf16 (2 VGPRs)
typedef float f32x4  __attribute__((ext_vector_type(4)));

__device__ __forceinline__ short f2bs(float x) {
  union { __hip_bfloat16 b; short s; } u;
  u.b = __float2bfloat16(x);
  return u.s;
}
__device__ __forceinline__ bfrag8 cvt8(const float* v) {
  bfrag8 r;
#pragma unroll
  for (int i = 0; i < 8; ++i) r[i] = f2bs(v[i]);
  return r;
}
__device__ __forceinline__ bfrag4 cvt4(float a, float b, float c, float d) {
  bfrag4 r;
  r[0] = f2bs(a); r[1] = f2bs(b); r[2] = f2bs(c); r[3] = f2bs(d);
  return r;
}
__device__ __forceinline__ void async_copy16(const void* g, void* l) {
  __builtin_amdgcn_global_load_lds((const __attribute__((address_space(1))) void*)g,
                                   (__attribute__((address_space(3))) void*)l, 16, 0, 0);
}

// K=16 bf16 MFMA (A,B: 4 bf16/lane, k = quad*4+j — matches C-layout row index).
#if defined(__has_builtin)
#  if __has_builtin(__builtin_amdgcn_mfma_f32_16x16x16bf16_1k)
#    define HAVE_MFMA16X16X16 1
#  endif
#endif
__device__ __forceinline__ f32x4 mfma16(bfrag4 a, bfrag4 b, f32x4 c) {
#ifdef HAVE_MFMA16X16X16
  return __builtin_amdgcn_mfma_f32_16x16x16bf16_1k(a, b, c, 0, 0, 0);
#else
  f32x4 d;
  asm volatile("v_mfma_f32_16x16x16_bf16 %0, %1, %2, %3"
               : "=v"(d) : "v"(a), "v"(b), "v"(c));
  return d;
#endif
}

// Intra-wave LDS fence: orders ds_write -> ds_read across lanes of ONE wave.
// lgkmcnt-only (no vmcnt drain => global prefetch stays in flight).
__device__ __forceinline__ void lds_fence() {
  asm volatile("s_waitcnt lgkmcnt(0)" ::: "memory");
  __builtin_amdgcn_sched_barrier(0);
}

// ---------------- bf16 MFMA GEMM: C[M,N] = A[M,K] @ Bt[N,K]^T (+bias) --------
__global__ __launch_bounds__(256) void gemm_bf16_kernel(
    const __hip_bfloat16* __restrict__ A,   // M x K row-major
    const __hip_bfloat16* __restrict__ Bt,  // N x K row-major (B transposed)
    const float* __restrict__ bias, float* __restrict__ C,
    int M, int Kd, int Nd)
{
  __shared__ short sA[128 * 64];
  __shared__ short sB[128 * 64];
  const int t = threadIdx.x;
  const int w = t >> 6, lane = t & 63;
  const int quad = lane >> 4, li = lane & 15;
  const int wm = w & 1, wn = w >> 1;
  const int m0 = blockIdx.y * 128, n0 = blockIdx.x * 128;

  f32x4 acc[4][4];
#pragma unroll
  for (int mt = 0; mt < 4; ++mt)
#pragma unroll
    for (int nt = 0; nt < 4; ++nt) acc[mt][nt] = (f32x4){0.f, 0.f, 0.f, 0.f};

  const __hip_bfloat16* Ab = A + (size_t)m0 * Kd;
  const __hip_bfloat16* Bb = Bt + (size_t)n0 * Kd;

#pragma unroll 1
  for (int k0 = 0; k0 < Kd; k0 += 64) {
    __syncthreads();
#pragma unroll
    for (int i = 0; i < 4; ++i) {
      int c = i * 256 + t;
      int row = c >> 3;
      int gl = (c & 7) ^ (row & 7);
      async_copy16(Ab + (size_t)row * Kd + k0 + gl * 8, &sA[c * 8]);
      async_copy16(Bb + (size_t)row * Kd + k0 + gl * 8, &sB[c * 8]);
    }
    __syncthreads();
#pragma unroll
    for (int ks = 0; ks < 2; ++ks) {
      bfrag8 aF[4], bF[4];
#pragma unroll
      for (int mt = 0; mt < 4; ++mt) {
        int row = wm * 64 + mt * 16 + li;
        int gi = (ks * 4 + quad) ^ (row & 7);
        aF[mt] = *(const bfrag8*)(&sA[row * 64 + gi * 8]);
      }
#pragma unroll
      for (int nt = 0; nt < 4; ++nt) {
        int row = wn * 64 + nt * 16 + li;
        int gi = (ks * 4 + quad) ^ (row & 7);
        bF[nt] = *(const bfrag8*)(&sB[row * 64 + gi * 8]);
      }
#pragma unroll
      for (int mt = 0; mt < 4; ++mt)
#pragma unroll
        for (int nt = 0; nt < 4; ++nt)
          acc[mt][nt] = __builtin_amdgcn_mfma_f32_16x16x32_bf16(aF[mt], bF[nt], acc[mt][nt], 0, 0, 0);
    }
  }

#pragma unroll
  for (int mt = 0; mt < 4; ++mt)
#pragma unroll
    for (int nt = 0; nt < 4; ++nt) {
      int ncol = n0 + wn * 64 + nt * 16 + li;
      float bv = bias ? bias[ncol] : 0.f;
#pragma unroll
      for (int r = 0; r < 4; ++r) {
        int mrow = m0 + wm * 64 + mt * 16 + quad * 4 + r;
        C[(size_t)mrow * Nd + ncol] = acc[mt][nt][r] + bv;
      }
    }
}

// ---------------- f32 -> bf16 cast (x4 vectorized) ---------------------------
__global__ __launch_bounds__(256) void cast_bf16_kernel(
    const float* __restrict__ in, __hip_bfloat16* __restrict__ out, int n4)
{
  int i = blockIdx.x * 256 + threadIdx.x;
  if (i >= n4) return;
  float4 v = ((const float4*)in)[i];
  union { short b[4]; short4 s; } u;
  u.b[0] = f2bs(v.x); u.b[1] = f2bs(v.y); u.b[2] = f2bs(v.z); u.b[3] = f2bs(v.w);
  ((short4*)out)[i] = u.s;
}

// ---------------- transpose + cast: Bt[n][k] = (bf16)B[k][n] -----------------
__global__ __launch_bounds__(256) void transpose_cast_kernel(
    const float* __restrict__ B, __hip_bfloat16* __restrict__ Bt, int Kd, int Nd)
{
  __shared__ float tl[64][65];
  int k0 = blockIdx.x * 64, n0 = blockIdx.y * 64;
  int tx = threadIdx.x & 63, ty = threadIdx.x >> 6;
#pragma unroll
  for (int i = 0; i < 16; ++i) {
    int k = ty + i * 4;
    tl[k][tx] = B[(size_t)(k0 + k) * Nd + n0 + tx];
  }
  __syncthreads();
#pragma unroll
  for (int i = 0; i < 16; ++i) {
    int n = ty + i * 4;
    Bt[(size_t)(n0 + n) * Kd + k0 + tx] = __float2bfloat16(tl[tx][n]);
  }
}

// ---------------- lr = sigmoid(xx @ lr_w + lr_b) / hd ------------------------
__global__ __launch_bounds__(256) void lr_kernel(
    const float* __restrict__ x, const float* __restrict__ lr_w,
    const float* __restrict__ lr_b, float* __restrict__ lrout)
{
  int idx = blockIdx.x * 256 + threadIdx.x;
  if (idx >= Bq * Nseq * NH2) return;
  int hh = idx % NH2;
  int row = idx / NH2;
  int b = row >> 10, n = row & 1023;
  const float* x1 = x + (size_t)row * Cdim;
  const float* x2 = x + (size_t)(b * Nseq + (Nseq - 1 - n)) * Cdim;
  float acc = lr_b[hh];
  for (int c = 0; c < Cdim; ++c) acc += x1[c] * lr_w[c * NH2 + hh];
  for (int c = 0; c < Cdim; ++c) acc += x2[c] * lr_w[(Cdim + c) * NH2 + hh];
  float sg = 1.f / (1.f + expf(-acc));
  lrout[idx] = sg * (1.f / 64.f);
}

// ---------------- single-wave MFMA TTT scan: one WAVE per (b,h) chain --------
// 64 threads/block, grid = 384. All cross-channel reductions are in-wave
// (register adds over the 4 output tiles + shfl_xor over li); block barriers
// are replaced by intra-wave lgkmcnt fences. The K=16 MFMAs use
// mfma_f32_16x16x16_bf16 whose A/B frag k-index (quad*4+j) equals the MFMA
// C-layout row index (quad*4+r), so bGrad/aXk come straight from registers
// (no sGT/sKT LDS transposes).
// Frag layouts: A[m=li][k], B[n=li][k]; C/D: col=li, row=quad*4+reg.
__global__ __launch_bounds__(64, 1) void ttt_scan1_kernel(
    const float* __restrict__ qkv,   // (B,N,2304)
    const float* __restrict__ lrg,   // (B,N,24)
    const float* __restrict__ W1,    // (24,64,64) [ch_in][ch_out]
    const float* __restrict__ b1g,   // (24,64)
    const float* __restrict__ lnw,   // (24,64)
    const float* __restrict__ lnb,   // (24,64)
    const float* __restrict__ tid,   // (16,)
    float* __restrict__ Zout)        // (B,N,1536)
{
  __shared__ float sQ[16 * 68], sK[16 * 68], sV[16 * 68];  // rotary'd tiles [tok][ch]
  __shared__ float sC[16 * 20];     // coef [i][j] (transpose scratch)
  __shared__ float sWT[64 * 68];    // G [out_ch][in_ch]

  const int l = threadIdx.x;            // 0..63
  const int quad = l >> 4, li = l & 15;
  const int bh = blockIdx.x, b = bh / NH2, h = bh % NH2;
  const int chan = (h < 12) ? h * 64 : (h - 12) * 64;
  const bool flip = (h >= 12);
  const int bN = b * Nseq;

  // W state, B-frag layout per out-tile t: Wf[t][c][j] = W[c*32+quad*8+j][t*16+li]
  float Wf[4][2][8];
  bfrag8 wB[4][2];
#pragma unroll
  for (int t = 0; t < 4; ++t)
#pragma unroll
    for (int c = 0; c < 2; ++c) {
#pragma unroll
      for (int j = 0; j < 8; ++j)
        Wf[t][c][j] = W1[h * 4096 + (c * 32 + quad * 8 + j) * 64 + t * 16 + li];
      wB[t][c] = cvt8(Wf[t][c]);
    }
  float bC[4], gv[4], bt_[4];
#pragma unroll
  for (int t = 0; t < 4; ++t) {
    bC[t]  = b1g[h * 64 + t * 16 + li];
    gv[t]  = lnw[h * 64 + t * 16 + li];
    bt_[t] = lnb[h * 64 + t * 16 + li];
  }

  float tokC[4];
#pragma unroll
  for (int r = 0; r < 4; ++r) {
    int i = quad * 4 + r;
    float tk = 1.f / (float)(i + 1) + tid[i];
    tokC[r] = tk > 0.f ? tk : 0.f;
  }
  float t15 = 1.f / 16.f + tid[15];
  t15 = t15 > 0.f ? t15 : 0.f;

  // rotary tables: lane stages token l>>2, channels (l&3)*16 .. +15
  float c8[8], s8[8];
  {
    int pos = l >> 2;
#pragma unroll
    for (int pl = 0; pl < 8; ++pl) {
      int p = (l & 3) * 8 + pl;
      float inv = __expf(-((float)(2 * p) * (1.f / 64.f)) * 9.210340371976184f);
      float a = (float)pos * inv;
      c8[pl] = cosf(a);
      s8[pl] = sinf(a);
    }
  }

  // prefetch regs (q,k,v for tile m=0) + lr
  float4 pf[3][4];
  float pflr;
  {
    int nn = l >> 2;
    int grow = flip ? (bN + Nseq - 1 - nn) : (bN + nn);
#pragma unroll
    for (int a = 0; a < 3; ++a) {
      const float* bse = qkv + (size_t)grow * 2304 + chan + a * 768 + (l & 3) * 16;
#pragma unroll
      for (int i = 0; i < 4; ++i) pf[a][i] = ((const float4*)bse)[i];
    }
    pflr = lrg[(size_t)(bN + li) * NH2 + h];
  }

#pragma unroll 1
  for (int m = 0; m < NMB; ++m) {
    const int n0 = m * KB;

    // ---- stage from prefetch regs (rotary on q,k) ----
#pragma unroll
    for (int a = 0; a < 3; ++a) {
      float v16[16];
      *(float4*)(v16)      = pf[a][0]; *(float4*)(v16 + 4)  = pf[a][1];
      *(float4*)(v16 + 8)  = pf[a][2]; *(float4*)(v16 + 12) = pf[a][3];
      if (a < 2) {
#pragma unroll
        for (int pl = 0; pl < 8; ++pl) {
          float e = v16[2 * pl], o = v16[2 * pl + 1];
          v16[2 * pl]     = e * c8[pl] - o * s8[pl];
          v16[2 * pl + 1] = o * c8[pl] + e * s8[pl];
        }
      }
      float* dst = (a == 0 ? sQ : (a == 1 ? sK : sV)) + (l >> 2) * 68 + (l & 3) * 16;
#pragma unroll
      for (int i = 0; i < 4; ++i) ((f32x4*)dst)[i] = *(f32x4*)(v16 + 4 * i);
    }
    float lrl = pflr;
    lds_fence();                                  // S1: staging visible

    // ---- issue global prefetch for m+1 (never force-drained in this loop) ----
    if (m < NMB - 1) {
      int nn = (m + 1) * KB + (l >> 2);
      int grow = flip ? (bN + Nseq - 1 - nn) : (bN + nn);
#pragma unroll
      for (int a = 0; a < 3; ++a) {
        const float* bse = qkv + (size_t)grow * 2304 + chan + a * 768 + (l & 3) * 16;
#pragma unroll
        for (int i = 0; i < 4; ++i) pf[a][i] = ((const float4*)bse)[i];
      }
      pflr = lrg[(size_t)(bN + (m + 1) * KB + li) * NH2 + h];
    }

    // ---- A-frags (rows li) + C-layout reads ----
    bfrag8 aQ[2], aK[2];
#pragma unroll
    for (int c = 0; c < 2; ++c) {
      float tq[8], tk8[8];
      *(f32x4*)(tq)      = *(const f32x4*)(&sQ[li * 68 + c * 32 + quad * 8]);
      *(f32x4*)(tq + 4)  = *(const f32x4*)(&sQ[li * 68 + c * 32 + quad * 8 + 4]);
      *(f32x4*)(tk8)     = *(const f32x4*)(&sK[li * 68 + c * 32 + quad * 8]);
      *(f32x4*)(tk8 + 4) = *(const f32x4*)(&sK[li * 68 + c * 32 + quad * 8 + 4]);
      aQ[c] = cvt8(tq);
      aK[c] = cvt8(tk8);
    }
    float kCv[4][4], vCv[4][4], qCv[4][4];   // [tile][r] = tok(quad*4+r), ch(t*16+li)
#pragma unroll
    for (int t = 0; t < 4; ++t)
#pragma unroll
      for (int r = 0; r < 4; ++r) {
        int off = (quad * 4 + r) * 68 + t * 16 + li;
        kCv[t][r] = sK[off]; vCv[t][r] = sV[off]; qCv[t][r] = sQ[off];
      }

    // ---- MFMA: Z1 (4 tiles), xqW (4 tiles), attn ----
    f32x4 accZ[4], accQ[4];
#pragma unroll
    for (int t = 0; t < 4; ++t) {
      accZ[t] = (f32x4){0.f, 0.f, 0.f, 0.f};
      accQ[t] = (f32x4){0.f, 0.f, 0.f, 0.f};
#pragma unroll
      for (int c = 0; c < 2; ++c) {
        accZ[t] = __builtin_amdgcn_mfma_f32_16x16x32_bf16(aK[c], wB[t][c], accZ[t], 0, 0, 0);
        accQ[t] = __builtin_amdgcn_mfma_f32_16x16x32_bf16(aQ[c], wB[t][c], accQ[t], 0, 0, 0);
      }
    }
    {
      f32x4 accA = (f32x4){0.f, 0.f, 0.f, 0.f};
      accA = __builtin_amdgcn_mfma_f32_16x16x32_bf16(aQ[0], aK[0], accA, 0, 0, 0);
      accA = __builtin_amdgcn_mfma_f32_16x16x32_bf16(aQ[1], aK[1], accA, 0, 0, 0);
#pragma unroll
      for (int r = 0; r < 4; ++r) {
        int i = quad * 4 + r;
        sC[i * 20 + li] = (li <= i) ? (-tokC[r] * (accA[r] + 1.f)) : 0.f;
      }
    }

    // ---- LN-L2 backward: all reductions in-wave ----
    float gs[4][4];
#pragma unroll
    for (int r = 0; r < 4; ++r) {
      float zt[4], xht[4], gxht[4];
      float s1 = 0.f, s2 = 0.f;
#pragma unroll
      for (int t = 0; t < 4; ++t) {
        zt[t] = accZ[t][r] + bC[t];
        s1 += zt[t];
        s2 += zt[t] * zt[t];
      }
#pragma unroll
      for (int o = 1; o < 16; o <<= 1) { s1 += __shfl_xor(s1, o); s2 += __shfl_xor(s2, o); }
      float mu = s1 * 0.015625f;
      float var = s2 * 0.015625f - mu * mu;
      float rstd = rsqrtf(var + 1e-6f);
      float r1 = 0.f, r2 = 0.f;
#pragma unroll
      for (int t = 0; t < 4; ++t) {
        xht[t] = (zt[t] - mu) * rstd;
        float gout = gv[t] * xht[t] + bt_[t] - (vCv[t][r] - kCv[t][r]);
        gxht[t] = gout * gv[t];
        r1 += gxht[t];
        r2 += gxht[t] * xht[t];
      }
#pragma unroll
      for (int o = 1; o < 16; o <<= 1) { r1 += __shfl_xor(r1, o); r2 += __shfl_xor(r2, o); }
      float lrr = __shfl(lrl, quad * 4 + r);
#pragma unroll
      for (int t = 0; t < 4; ++t) {
        float gd = (64.f * gxht[t] - r1 - xht[t] * r2) * rstd * 0.015625f;
        gs[t][r] = lrr * gd;
      }
    }

    // ---- K=16 frags straight from registers (C-layout == frag k-layout) ----
    bfrag4 bGrad[4], aXk[4];
#pragma unroll
    for (int t = 0; t < 4; ++t) {
      bGrad[t] = cvt4(gs[t][0], gs[t][1], gs[t][2], gs[t][3]);
      aXk[t]   = cvt4(kCv[t][0], kCv[t][1], kCv[t][2], kCv[t][3]);
    }
    lds_fence();                                  // S2: sC visible
    bfrag4 aCoef;
    {
      f32x4 cf = *(const f32x4*)(&sC[li * 20 + quad * 4]);
      aCoef = cvt4(cf[0], cf[1], cf[2], cf[3]);
    }

    // ---- Z1_bar = xqW + b + coef@gradS ; LN ; output ----
    f32x4 zb[4];
#pragma unroll
    for (int t = 0; t < 4; ++t) {
      f32x4 acc = accQ[t];
#pragma unroll
      for (int r = 0; r < 4; ++r) acc[r] += bC[t];
      zb[t] = mfma16(aCoef, bGrad[t], acc);
    }
#pragma unroll
    for (int r = 0; r < 4; ++r) {
      float s1 = 0.f, s2 = 0.f;
#pragma unroll
      for (int t = 0; t < 4; ++t) { s1 += zb[t][r]; s2 += zb[t][r] * zb[t][r]; }
#pragma unroll
      for (int o = 1; o < 16; o <<= 1) { s1 += __shfl_xor(s1, o); s2 += __shfl_xor(s2, o); }
      float mu = s1 * 0.015625f;
      float var = s2 * 0.015625f - mu * mu;
      float rstd = rsqrtf(var + 1e-6f);
#pragma unroll
      for (int t = 0; t < 4; ++t) {
        float outv = qCv[t][r] + gv[t] * (zb[t][r] - mu) * rstd + bt_[t];
        Zout[(size_t)(bN + n0 + quad * 4 + r) * W2D + h * 64 + t * 16 + li] = outv;
      }
    }

    // ---- G = xk^T @ gradS (16 tiles) -> LDS -> W-frag redistribution ----
#pragma unroll
    for (int nt = 0; nt < 4; ++nt)
#pragma unroll
      for (int mt = 0; mt < 4; ++mt) {
        f32x4 g = mfma16(aXk[mt], bGrad[nt], (f32x4){0.f, 0.f, 0.f, 0.f});
        *(f32x4*)(&sWT[(nt * 16 + li) * 68 + mt * 16 + quad * 4]) = g;
      }
    lds_fence();                                  // S3: sWT visible
#pragma unroll
    for (int t = 0; t < 4; ++t) {
#pragma unroll
      for (int c = 0; c < 2; ++c) {
        float w8[8];
        *(f32x4*)(w8)     = *(const f32x4*)(&sWT[(t * 16 + li) * 68 + c * 32 + quad * 8]);
        *(f32x4*)(w8 + 4) = *(const f32x4*)(&sWT[(t * 16 + li) * 68 + c * 32 + quad * 8 + 4]);
#pragma unroll
        for (int j = 0; j < 8; ++j) Wf[t][c][j] -= t15 * w8[j];
        wB[t][c] = cvt8(Wf[t][c]);
      }
      float g0 = gs[t][0] + gs[t][1] + gs[t][2] + gs[t][3];
      g0 += __shfl_xor(g0, 16);
      g0 += __shfl_xor(g0, 32);
      bC[t] -= t15 * g0;
    }
    // Next-iter staging writes (sQ/sK/sV) conflict only with reads completed
    // before S2; sWT reads here complete before next iter's S1 drain. No extra
    // fence needed.
  }
}

// ---------------- post-LN over W2=1536 ---------------------------------------
__global__ __launch_bounds__(256) void postln_kernel(
    const float* __restrict__ Z, const float* __restrict__ wv,
    const float* __restrict__ bb, float* __restrict__ out)
{
  __shared__ float red[8];
  const int row = blockIdx.x;
  const int t = threadIdx.x;
  const float* zr = Z + (size_t)row * W2D;
  float vals[6];
  float s1 = 0.f, s2 = 0.f;
#pragma unroll
  for (int r = 0; r < 6; ++r) { float v = zr[t + 256 * r]; vals[r] = v; s1 += v; s2 += v * v; }
#pragma unroll
  for (int o = 1; o < 64; o <<= 1) { s1 += __shfl_xor(s1, o); s2 += __shfl_xor(s2, o); }
  if ((t & 63) == 0) { red[t >> 6] = s1; red[4 + (t >> 6)] = s2; }
  __syncthreads();
  s1 = red[0] + red[1] + red[2] + red[3];
  s2 = red[4] + red[5] + red[6] + red[7];
  float mu = s1 * (1.f / 1536.f);
  float var = s2 * (1.f / 1536.f) - mu * mu;
  float rstd = rsqrtf(var + 1e-6f);
  float* orow = out + (size_t)row * W2D;
#pragma unroll
  for (int r = 0; r < 6; ++r) {
    int c = t + 256 * r;
    orow[c] = wv[c] * (vals[r] - mu) * rstd + bb[c];
  }
}

// ---------------- h(bf16)[b,n,c] = Zln[b,n,c] * Zln[b,N-1-n,768+c] -----------
__global__ __launch_bounds__(256) void mult_bf16_kernel(
    const float* __restrict__ Zln, __hip_bfloat16* __restrict__ hbuf)
{
  int idx = blockIdx.x * 256 + threadIdx.x;
  int c4 = (idx % (Cdim / 4)) * 4;
  int row = idx / (Cdim / 4);
  int b = row >> 10, n = row & 1023;
  float4 zf = *(const float4*)(&Zln[(size_t)row * W2D + c4]);
  float4 zb = *(const float4*)(&Zln[(size_t)(b * Nseq + (Nseq - 1 - n)) * W2D + Cdim + c4]);
  union { short b4[4]; short4 s; } u;
  u.b4[0] = f2bs(zf.x * zb.x); u.b4[1] = f2bs(zf.y * zb.y);
  u.b4[2] = f2bs(zf.z * zb.z); u.b4[3] = f2bs(zf.w * zb.w);
  *(short4*)(&hbuf[(size_t)row * Cdim + c4]) = u.s;
}

// ---------------- launch -----------------------------------------------------
extern "C" void kernel_launch(void* const* d_in, const int* in_sizes, int n_in,
                              void* d_out, int out_size, void* d_ws, size_t ws_size,
                              hipStream_t stream)
{
  const float* x         = (const float*)d_in[0];
  const float* qkv_w     = (const float*)d_in[1];
  const float* proj_w    = (const float*)d_in[2];
  const float* proj_b    = (const float*)d_in[3];
  const float* W1        = (const float*)d_in[4];
  const float* b1        = (const float*)d_in[5];
  const float* ttt_ln_w  = (const float*)d_in[6];
  const float* ttt_ln_b  = (const float*)d_in[7];
  const float* post_ln_w = (const float*)d_in[8];
  const float* post_ln_b = (const float*)d_in[9];
  const float* lr_w      = (const float*)d_in[10];
  const float* lr_b      = (const float*)d_in[11];
  const float* tid       = (const float*)d_in[12];
  float* out = (float*)d_out;
  float* ws  = (float*)d_ws;

  float* qkv   = ws;                                   // [0, 37748736)
  float* lrbuf = ws + 37748736;                        // [.., 38141952)
  float* Zbuf  = ws + 38141952;                        // [.., 63307776)
  __hip_bfloat16* xbf    = (__hip_bfloat16*)(ws + 38141952);
  __hip_bfloat16* wqkv_t = (__hip_bfloat16*)(ws + 44433408);
  float* Zln             = ws;
  __hip_bfloat16* hbf    = (__hip_bfloat16*)(ws + 25165824);
  __hip_bfloat16* wproj_t= (__hip_bfloat16*)(ws + 38141952);

  const int Mrows = Bq * Nseq;             // 16384

  cast_bf16_kernel<<<(Mrows * Cdim / 4 + 255) / 256, 256, 0, stream>>>(x, xbf, Mrows * Cdim / 4);
  {
    dim3 g(Cdim / 64, 3 * Cdim / 64);
    transpose_cast_kernel<<<g, 256, 0, stream>>>(qkv_w, wqkv_t, Cdim, 3 * Cdim);
  }
  {
    dim3 g(3 * Cdim / 128, Mrows / 128);
    gemm_bf16_kernel<<<g, 256, 0, stream>>>(xbf, wqkv_t, nullptr, qkv, Mrows, Cdim, 3 * Cdim);
  }
  lr_kernel<<<(Mrows * NH2 + 255) / 256, 256, 0, stream>>>(x, lr_w, lr_b, lrbuf);

  ttt_scan1_kernel<<<Bq * NH2, 64, 0, stream>>>(qkv, lrbuf, W1, b1, ttt_ln_w, ttt_ln_b, tid, Zbuf);

  postln_kernel<<<Mrows, 256, 0, stream>>>(Zbuf, post_ln_w, post_ln_b, Zln);
  {
    dim3 g(Cdim / 64, Cdim / 64);
    transpose_cast_kernel<<<g, 256, 0, stream>>>(proj_w, wproj_t, Cdim, Cdim);
  }
  mult_bf16_kernel<<<(Mrows * Cdim / 4) / 256, 256, 0, stream>>>(Zln, hbf);
  {
    dim3 g(Cdim / 128, Mrows / 128);
    gemm_bf16_kernel<<<g, 256, 0, stream>>>(hbf, wproj_t, proj_b, out, Mrows, Cdim, Cdim);
  }
}